// Round 2
// baseline (522.400 us; speedup 1.0000x reference)
//
#include <hip/hip_runtime.h>

#define NN 74240      // nodes
#define NE 593920     // edges
#define DIN 75
#define DD 128
#define NL 3
#define EPS 1e-5f
#define NB 290        // scan blocks: 290*256 == NN
#define NT (NN / 64)  // 1160 row-tiles for k_layer
#define GL 512        // persistent k_layer grid: 2 blocks/CU x 256 CU
#define NREP 64       // replicated BN-sum buffers (contention 1160 -> 8 per addr)

typedef __attribute__((ext_vector_type(8))) short short8;   // 8 bf16 = 4 VGPRs (MFMA A/B frag)
typedef __attribute__((ext_vector_type(4))) float f32x4;    // MFMA C/D frag

// fp32 -> bf16 with round-to-nearest-even
static __device__ __forceinline__ unsigned short f2bf(float f) {
    union { float f; unsigned u; } v; v.f = f;
    unsigned u = v.u;
    unsigned r = (u + 0x7fffu + ((u >> 16) & 1u)) >> 16;
    return (unsigned short)r;
}

// ---------------- init GEMM: h = X @ W_init  ([NN,75] @ [75,128]) ----------------
// 256 threads = 4 waves per 64-row tile; wave w owns cols [w*32, w*32+32).
// Col-group is wave-uniform (readfirstlane) -> W loads are scalar s_load broadcasts.
__global__ __launch_bounds__(256) void k_init(const float* __restrict__ X,
                                              const float* __restrict__ W,
                                              float* __restrict__ h) {
    __shared__ float sX[64 * DIN];            // 19200 B -> 8 blocks/CU LDS cap
    const int tid = threadIdx.x;
    const int r0 = blockIdx.x * 64;
    {   // stage 64 rows of X, float4-vectorized (64*75/4 = 1200 float4)
        const float4* Xv = (const float4*)(X + (size_t)r0 * DIN);
        float4* sv = (float4*)sX;
        #pragma unroll
        for (int i = 0; i < 4; ++i) sv[tid + i * 256] = Xv[tid + i * 256];
        if (tid < 1200 - 1024) sv[tid + 1024] = Xv[tid + 1024];
    }
    __syncthreads();
    const int lane = tid & 63;
    const int cg = __builtin_amdgcn_readfirstlane(tid >> 6) * 32;  // wave-uniform col group
    const float* xr = sX + lane * DIN;
    float acc[32];
    #pragma unroll
    for (int j = 0; j < 32; ++j) acc[j] = 0.0f;
    #pragma unroll 5
    for (int k = 0; k < DIN; ++k) {
        const float a = xr[k];
        const float* wk = W + k * DD + cg;    // uniform address -> scalar load
        #pragma unroll
        for (int j = 0; j < 32; ++j) acc[j] = fmaf(a, wk[j], acc[j]);
    }
    float* hrow = h + (size_t)(r0 + lane) * DD + cg;
    #pragma unroll
    for (int j = 0; j < 8; ++j) {
        float4 o = { acc[j * 4], acc[j * 4 + 1], acc[j * 4 + 2], acc[j * 4 + 3] };
        *(float4*)(hrow + j * 4) = o;
    }
}

// ---------------- weight prepack: fp32 [k][n] -> frag-ordered bf16 ----------------
// frag flat index: ((s*8 + t)*64 + (q*16 + (n&15)))*8 + j  with s=k/32, q=(k/8)%4, j=k%8, t=n/16
// -> each lane's B-frag is one contiguous 16B chunk (conflict-free ds_read_b128).
__global__ __launch_bounds__(256) void k_wprep(const float* __restrict__ Wg,
                                               const float* __restrict__ Wr,
                                               unsigned short* __restrict__ wf) {
    const int tid = blockIdx.x * 256 + threadIdx.x;   // grid*256 == NL*2*16384
    const int l = tid >> 15;
    const int m = (tid >> 14) & 1;
    const int e = tid & 16383;
    const int k = e >> 7, n = e & 127;
    const float* W = (m == 0 ? Wg : Wr) + l * 16384;
    const float v = W[e];
    const int s = k >> 5, q = (k >> 3) & 3, j = k & 7, t = n >> 4;
    const int ln = (q << 4) | (n & 15);
    const int idx = ((s * 8 + t) * 64 + ln) * 8 + j;
    wf[(l * 2 + m) * 16384 + idx] = f2bf(v);
}

// ---------------- CSR build: histogram -> 3-phase scan -> fill ----------------
__global__ __launch_bounds__(256) void k_hist(const int* __restrict__ dst, int* cnt) {
    const int e = blockIdx.x * 256 + threadIdx.x;   // grid == NE
    atomicAdd(&cnt[dst[e]], 1);
}

__global__ __launch_bounds__(256) void k_scan1(const int* __restrict__ cnt,
                                               int* __restrict__ bsum) {
    const int tid = threadIdx.x;
    int v = cnt[blockIdx.x * 256 + tid];
    #pragma unroll
    for (int off = 1; off < 64; off <<= 1) v += __shfl_xor(v, off, 64);
    __shared__ int ws[4];
    if ((tid & 63) == 0) ws[tid >> 6] = v;
    __syncthreads();
    if (tid == 0) bsum[blockIdx.x] = ws[0] + ws[1] + ws[2] + ws[3];
}

__global__ __launch_bounds__(512) void k_scan2(const int* __restrict__ bsum,
                                               int* __restrict__ boff) {
    __shared__ int s[512];
    const int t = threadIdx.x;
    const int v = (t < NB) ? bsum[t] : 0;
    s[t] = v;
    __syncthreads();
    for (int off = 1; off < 512; off <<= 1) {
        const int u = (t >= off) ? s[t - off] : 0;
        __syncthreads();
        s[t] += u;
        __syncthreads();
    }
    if (t < NB) boff[t] = s[t] - v;   // exclusive
}

__global__ __launch_bounds__(256) void k_scan3(const int* __restrict__ cnt,
                                               const int* __restrict__ boff,
                                               int* __restrict__ rowptr,
                                               int* __restrict__ offs) {
    const int tid = threadIdx.x;
    const int t = blockIdx.x * 256 + tid;
    const int lane = tid & 63;
    const int v = cnt[t];
    int inc = v;
    #pragma unroll
    for (int off = 1; off < 64; off <<= 1) {
        const int u = __shfl_up(inc, off, 64);
        if (lane >= off) inc += u;
    }
    __shared__ int ws[4];
    if (lane == 63) ws[tid >> 6] = inc;
    __syncthreads();
    const int w = tid >> 6;
    int waveoff = 0;
    for (int i = 0; i < 4; ++i) waveoff += (i < w) ? ws[i] : 0;
    const int excl = boff[blockIdx.x] + waveoff + inc - v;
    rowptr[t] = excl;
    offs[t] = excl;
    if (blockIdx.x == NB - 1 && tid == 255) rowptr[NN] = NE;
}

__global__ __launch_bounds__(256) void k_fill(const int* __restrict__ src,
                                              const int* __restrict__ dst,
                                              int* offs, int* __restrict__ col) {
    const int e = blockIdx.x * 256 + threadIdx.x;   // grid == NE
    const int pos = atomicAdd(&offs[dst[e]], 1);
    col[pos] = src[e];
}

// ---------------- BN affine-coefficient helpers ----------------
__global__ __launch_bounds__(256) void k_prep(float* __restrict__ ab0) {
    ab0[threadIdx.x] = (threadIdx.x < 128) ? 1.0f : 0.0f;   // identity for layer 0 input
}

// reduce NREP replicated partial-sum buffers -> affine (a,b) for next stage
__global__ __launch_bounds__(128) void k_stats(const float* __restrict__ srep,
                                               const float* __restrict__ gamma,
                                               const float* __restrict__ beta,
                                               float* __restrict__ ab) {
    const int c = threadIdx.x;
    float s = 0.f, q = 0.f;
    for (int r = 0; r < NREP; ++r) {
        s += srep[r * 256 + c];
        q += srep[r * 256 + 128 + c];
    }
    const float invN = 1.0f / (float)NN;
    const float mu = s * invN;
    const float var = q * invN - mu * mu;
    const float a = gamma[c] * rsqrtf(var + EPS);
    ab[c] = a;
    ab[128 + c] = beta[c] - a * mu;
}

// ---------------- gather (BN folded): agg[row] = a * sum_e h_raw[col[e]] + deg*b ----
__global__ __launch_bounds__(256) void k_gather(const float* __restrict__ h,
                                                const int* __restrict__ rowptr,
                                                const int* __restrict__ col,
                                                const float* __restrict__ ab,
                                                float* __restrict__ agg) {
    const int wave = threadIdx.x >> 6;
    const int lane = threadIdx.x & 63;
    const int row = blockIdx.x * 4 + wave;   // grid = NN/4
    const int eb = rowptr[row];
    const int ee = rowptr[row + 1];
    const int half = lane >> 5;
    const int f = (lane & 31) * 4;
    float4 a0 = {0.f,0.f,0.f,0.f}, a1 = {0.f,0.f,0.f,0.f};
    float4 a2 = {0.f,0.f,0.f,0.f}, a3 = {0.f,0.f,0.f,0.f};
    int e = eb + half;
    for (; e + 6 < ee; e += 8) {
        const int c0 = col[e], c1 = col[e + 2], c2 = col[e + 4], c3 = col[e + 6];
        const float4 v0 = *(const float4*)(h + (size_t)c0 * DD + f);
        const float4 v1 = *(const float4*)(h + (size_t)c1 * DD + f);
        const float4 v2 = *(const float4*)(h + (size_t)c2 * DD + f);
        const float4 v3 = *(const float4*)(h + (size_t)c3 * DD + f);
        a0.x += v0.x; a0.y += v0.y; a0.z += v0.z; a0.w += v0.w;
        a1.x += v1.x; a1.y += v1.y; a1.z += v1.z; a1.w += v1.w;
        a2.x += v2.x; a2.y += v2.y; a2.z += v2.z; a2.w += v2.w;
        a3.x += v3.x; a3.y += v3.y; a3.z += v3.z; a3.w += v3.w;
    }
    for (; e < ee; e += 2) {
        const int c = col[e];
        const float4 v = *(const float4*)(h + (size_t)c * DD + f);
        a0.x += v.x; a0.y += v.y; a0.z += v.z; a0.w += v.w;
    }
    float4 s;
    s.x = (a0.x + a1.x) + (a2.x + a3.x);
    s.y = (a0.y + a1.y) + (a2.y + a3.y);
    s.z = (a0.z + a1.z) + (a2.z + a3.z);
    s.w = (a0.w + a1.w) + (a2.w + a3.w);
    s.x += __shfl_xor(s.x, 32, 64);
    s.y += __shfl_xor(s.y, 32, 64);
    s.z += __shfl_xor(s.z, 32, 64);
    s.w += __shfl_xor(s.w, 32, 64);
    if (half == 0) {
        const float deg = (float)(ee - eb);
        const float4 av = *(const float4*)(ab + f);
        const float4 bv = *(const float4*)(ab + 128 + f);
        float4 o;
        o.x = fmaf(av.x, s.x, deg * bv.x);
        o.y = fmaf(av.y, s.y, deg * bv.y);
        o.z = fmaf(av.z, s.z, deg * bv.z);
        o.w = fmaf(av.w, s.w, deg * bv.w);
        *(float4*)(agg + (size_t)row * DD + f) = o;
    }
}

// ---------------- fused layer GEMMs via bf16 MFMA (persistent blocks) ----------------
// Grid = 512 (exactly 2 blocks/CU, the 65KB-LDS residency cap). Each block stages the
// 64KB frag-ordered weights ONCE, then grid-strides over the 1160 64-row tiles.
// BN partial sums accumulate in per-thread registers across tiles; one shfl-reduce at
// kernel end; global atomics go to 64 replicated buffers (8 blocks/replica).
__global__ __launch_bounds__(256, 2) void k_layer(const float* __restrict__ hin,
                                                  const float* __restrict__ aggin,
                                                  const unsigned short* __restrict__ wfrag,
                                                  const float* __restrict__ bg,
                                                  const float* __restrict__ br,
                                                  const float* __restrict__ ab,
                                                  float* __restrict__ h2out,
                                                  float* __restrict__ sumrep) {
    __shared__ unsigned short sBg[16384];   // 32 KB, frag-ordered Wg
    __shared__ unsigned short sBr[16384];   // 32 KB, frag-ordered Wr
    __shared__ float sSum[256];
    const int tid = threadIdx.x;

    {   // stage both weight-frag arrays once (coalesced b128 copies)
        const uint4* srcg = (const uint4*)wfrag;          // 2048 uint4
        const uint4* srcr = srcg + 2048;
        uint4* dg = (uint4*)sBg;
        uint4* dr = (uint4*)sBr;
        #pragma unroll
        for (int i = 0; i < 8; ++i) dg[tid + i * 256] = srcg[tid + i * 256];
        #pragma unroll
        for (int i = 0; i < 8; ++i) dr[tid + i * 256] = srcr[tid + i * 256];
        sSum[tid] = 0.0f;
    }
    __syncthreads();

    const int w = tid >> 6;          // wave 0..3
    const int lane = tid & 63;
    const int ln15 = lane & 15;
    const int q = lane >> 4;

    float bgc[8], brc[8];            // hoisted bias (per owned column)
    #pragma unroll
    for (int t = 0; t < 8; ++t) {
        bgc[t] = bg[t * 16 + ln15];
        brc[t] = br[t * 16 + ln15];
    }

    float svA[8], qvA[8];            // cross-tile BN partial sums (per owned column)
    #pragma unroll
    for (int t = 0; t < 8; ++t) { svA[t] = 0.f; qvA[t] = 0.f; }

    for (int tile = blockIdx.x; tile < NT; tile += GL) {
        const int r0 = tile * 64 + w * 16;   // wave's 16-row M-tile base
        const int arow = r0 + ln15;          // row this lane's A/H frag holds

        f32x4 accg[8], accr[8];
        #pragma unroll
        for (int t = 0; t < 8; ++t) {
            accg[t] = (f32x4){0.f, 0.f, 0.f, 0.f};
            accr[t] = (f32x4){0.f, 0.f, 0.f, 0.f};
        }

        #pragma unroll
        for (int s = 0; s < 4; ++s) {
            const int kk = s * 32 + q * 8;
            const float4 a0 = *(const float4*)(aggin + (size_t)arow * DD + kk);
            const float4 a1 = *(const float4*)(aggin + (size_t)arow * DD + kk + 4);
            const float4 h0 = *(const float4*)(hin + (size_t)arow * DD + kk);
            const float4 h1 = *(const float4*)(hin + (size_t)arow * DD + kk + 4);
            const float4 av0 = *(const float4*)(ab + kk);
            const float4 av1 = *(const float4*)(ab + kk + 4);
            const float4 bv0 = *(const float4*)(ab + 128 + kk);
            const float4 bv1 = *(const float4*)(ab + 128 + kk + 4);
            short8 af, hf;
            af[0] = (short)f2bf(a0.x); af[1] = (short)f2bf(a0.y);
            af[2] = (short)f2bf(a0.z); af[3] = (short)f2bf(a0.w);
            af[4] = (short)f2bf(a1.x); af[5] = (short)f2bf(a1.y);
            af[6] = (short)f2bf(a1.z); af[7] = (short)f2bf(a1.w);
            hf[0] = (short)f2bf(fmaf(av0.x, h0.x, bv0.x));
            hf[1] = (short)f2bf(fmaf(av0.y, h0.y, bv0.y));
            hf[2] = (short)f2bf(fmaf(av0.z, h0.z, bv0.z));
            hf[3] = (short)f2bf(fmaf(av0.w, h0.w, bv0.w));
            hf[4] = (short)f2bf(fmaf(av1.x, h1.x, bv1.x));
            hf[5] = (short)f2bf(fmaf(av1.y, h1.y, bv1.y));
            hf[6] = (short)f2bf(fmaf(av1.z, h1.z, bv1.z));
            hf[7] = (short)f2bf(fmaf(av1.w, h1.w, bv1.w));
            const int fb = s * 4096;   // frag base for this k-step
            #pragma unroll
            for (int t = 0; t < 8; ++t) {
                const short8 bgf = *(const short8*)&sBg[fb + (t * 64 + lane) * 8];
                const short8 brf = *(const short8*)&sBr[fb + (t * 64 + lane) * 8];
                accg[t] = __builtin_amdgcn_mfma_f32_16x16x32_bf16(af, bgf, accg[t], 0, 0, 0);
                accr[t] = __builtin_amdgcn_mfma_f32_16x16x32_bf16(hf, brf, accr[t], 0, 0, 0);
            }
        }

        // epilogue: bias + relu + add, store h2, accumulate BN sums in registers
        #pragma unroll
        for (int t = 0; t < 8; ++t) {
            const int c = t * 16 + ln15;
            #pragma unroll
            for (int r = 0; r < 4; ++r) {
                const int row = r0 + q * 4 + r;
                const float v = fmaxf(accg[t][r] + bgc[t], 0.f) + fmaxf(accr[t][r] + brc[t], 0.f);
                h2out[(size_t)row * DD + c] = v;
                svA[t] += v; qvA[t] += v * v;
            }
        }
    }

    // one reduction at kernel end
    #pragma unroll
    for (int t = 0; t < 8; ++t) {
        float sv = svA[t], qv = qvA[t];
        sv += __shfl_xor(sv, 16, 64); sv += __shfl_xor(sv, 32, 64);
        qv += __shfl_xor(qv, 16, 64); qv += __shfl_xor(qv, 32, 64);
        if (q == 0) {
            atomicAdd(&sSum[t * 16 + ln15], sv);
            atomicAdd(&sSum[128 + t * 16 + ln15], qv);
        }
    }
    __syncthreads();
    atomicAdd(&sumrep[(blockIdx.x & (NREP - 1)) * 256 + tid], sSum[tid]);
}

// ---------------- BatchNorm normalize (final layer): pure affine ----------------
__global__ __launch_bounds__(256) void k_bn(const float* __restrict__ h2,
                                            const float* __restrict__ ab,
                                            float* __restrict__ out) {
    const int t = blockIdx.x * 256 + threadIdx.x;  // NN*32 threads
    const size_t base = (size_t)t * 4;
    const int c = (int)(base & 127);
    const float4 v = *(const float4*)(h2 + base);
    const float4 a = *(const float4*)(ab + c);
    const float4 b = *(const float4*)(ab + 128 + c);
    float4 o;
    o.x = fmaf(a.x, v.x, b.x);
    o.y = fmaf(a.y, v.y, b.y);
    o.z = fmaf(a.z, v.z, b.z);
    o.w = fmaf(a.w, v.w, b.w);
    *(float4*)(out + base) = o;
}

extern "C" void kernel_launch(void* const* d_in, const int* in_sizes, int n_in,
                              void* d_out, int out_size, void* d_ws, size_t ws_size,
                              hipStream_t stream) {
    const float* X     = (const float*)d_in[0];
    const int*   src   = (const int*)d_in[1];
    const int*   dst   = (const int*)d_in[2];
    const float* Wi    = (const float*)d_in[3];
    const float* Wg    = (const float*)d_in[4];
    const float* bg    = (const float*)d_in[5];
    const float* Wr    = (const float*)d_in[6];
    const float* br    = (const float*)d_in[7];
    const float* gamma = (const float*)d_in[8];
    const float* beta  = (const float*)d_in[9];
    float* out = (float*)d_out;

    float* h      = (float*)d_ws;                         // [NN*DD]
    float* agg    = h + (size_t)NN * DD;                  // [NN*DD]
    float* sumrep = agg + (size_t)NN * DD;                // [NL*NREP*256]
    float* abv    = sumrep + (size_t)NL * NREP * 256;     // [(NL+1)*2*DD]  a/b per stage
    unsigned short* wfrag = (unsigned short*)(abv + (NL + 1) * 2 * DD);  // bf16 frags
    int* rowptr = (int*)(wfrag + NL * 2 * 16384);         // [NN+1]
    int* col    = rowptr + NN + 1;                        // [NE]
    int* bsum   = col + NE;                               // [NB]
    int* boff   = bsum + NB;                              // [NB]
    // CSR-build scratch aliased into agg (dead once k_fill completes)
    int* cnt    = (int*)agg;                              // [NN]
    int* offs   = cnt + NN;                               // [NN]

    hipMemsetAsync(sumrep, 0, (size_t)NL * NREP * 256 * sizeof(float), stream);
    hipMemsetAsync(cnt, 0, NN * sizeof(int), stream);

    k_prep<<<1, 256, 0, stream>>>(abv);               // identity a=1,b=0 for layer 0
    k_init<<<NN / 64, 256, 0, stream>>>(X, Wi, h);
    k_wprep<<<(NL * 2 * 16384) / 256, 256, 0, stream>>>(Wg, Wr, wfrag);
    k_hist<<<NE / 256, 256, 0, stream>>>(dst, cnt);
    k_scan1<<<NB, 256, 0, stream>>>(cnt, bsum);
    k_scan2<<<1, 512, 0, stream>>>(bsum, boff);
    k_scan3<<<NB, 256, 0, stream>>>(cnt, boff, rowptr, offs);
    k_fill<<<NE / 256, 256, 0, stream>>>(src, dst, offs, col);

    // raw-activation buffers alternate: h -> out -> h -> out (final BN in-place on out)
    const float* hcur = h;
    float* h2bufs[NL] = { out, h, out };
    for (int l = 0; l < NL; ++l) {
        const float* abl = abv + l * 2 * DD;
        float* h2 = h2bufs[l];
        k_gather<<<NN / 4, 256, 0, stream>>>(hcur, rowptr, col, abl, agg);
        k_layer<<<GL, 256, 0, stream>>>(hcur, agg,
                                        wfrag + l * 2 * 16384,
                                        bg + l * DD, br + l * DD,
                                        abl, h2, sumrep + (size_t)l * NREP * 256);
        k_stats<<<1, 128, 0, stream>>>(sumrep + (size_t)l * NREP * 256, gamma + l * DD,
                                       beta + l * DD, abv + (l + 1) * 2 * DD);
        if (l == NL - 1) {
            k_bn<<<(NN * 32) / 256, 256, 0, stream>>>(h2, abv + NL * 2 * DD, out);
        }
        hcur = h2;
    }
}

// Round 3
// 385.909 us; speedup vs baseline: 1.3537x; 1.3537x over previous
//
#include <hip/hip_runtime.h>

#define NN 74240      // nodes
#define NE 593920     // edges
#define DIN 75
#define DD 128
#define NL 3
#define EPS 1e-5f
#define NB 290        // scan blocks: 290*256 == NN
#define NT (NN / 64)  // 1160 row-tiles for k_layer
#define NREP 64       // replicated BN-sum buffers

typedef __attribute__((ext_vector_type(8))) short short8;   // 8 bf16 = 4 VGPRs (MFMA A/B frag)
typedef __attribute__((ext_vector_type(4))) float f32x4;    // MFMA C/D frag

// fp32 -> bf16 with round-to-nearest-even
static __device__ __forceinline__ unsigned short f2bf(float f) {
    union { float f; unsigned u; } v; v.f = f;
    unsigned u = v.u;
    unsigned r = (u + 0x7fffu + ((u >> 16) & 1u)) >> 16;
    return (unsigned short)r;
}

// ---------------- init GEMM: h = X @ W_init  ([NN,75] @ [75,128]) ----------------
// 256 threads = 4 waves per 64-row tile; wave w owns cols [w*32, w*32+32).
// Col-group is wave-uniform (readfirstlane) -> W loads are scalar s_load broadcasts.
__global__ __launch_bounds__(256) void k_init(const float* __restrict__ X,
                                              const float* __restrict__ W,
                                              float* __restrict__ h) {
    __shared__ float sX[64 * DIN];            // 19200 B -> 8 blocks/CU LDS cap
    const int tid = threadIdx.x;
    const int r0 = blockIdx.x * 64;
    {   // stage 64 rows of X, float4-vectorized (64*75/4 = 1200 float4)
        const float4* Xv = (const float4*)(X + (size_t)r0 * DIN);
        float4* sv = (float4*)sX;
        #pragma unroll
        for (int i = 0; i < 4; ++i) sv[tid + i * 256] = Xv[tid + i * 256];
        if (tid < 1200 - 1024) sv[tid + 1024] = Xv[tid + 1024];
    }
    __syncthreads();
    const int lane = tid & 63;
    const int cg = __builtin_amdgcn_readfirstlane(tid >> 6) * 32;  // wave-uniform col group
    const float* xr = sX + lane * DIN;
    float acc[32];
    #pragma unroll
    for (int j = 0; j < 32; ++j) acc[j] = 0.0f;
    #pragma unroll 5
    for (int k = 0; k < DIN; ++k) {
        const float a = xr[k];
        const float* wk = W + k * DD + cg;    // uniform address -> scalar load
        #pragma unroll
        for (int j = 0; j < 32; ++j) acc[j] = fmaf(a, wk[j], acc[j]);
    }
    float* hrow = h + (size_t)(r0 + lane) * DD + cg;
    #pragma unroll
    for (int j = 0; j < 8; ++j) {
        float4 o = { acc[j * 4], acc[j * 4 + 1], acc[j * 4 + 2], acc[j * 4 + 3] };
        *(float4*)(hrow + j * 4) = o;
    }
}

// ---------------- weight prepack: fp32 [k][n] -> frag-ordered bf16 ----------------
// frag flat index: ((s*8 + t)*64 + (q*16 + (n&15)))*8 + j  with s=k/32, q=(k/8)%4, j=k%8, t=n/16
// -> each lane's B-frag is one contiguous 16B chunk (coalesced global b128 reads).
__global__ __launch_bounds__(256) void k_wprep(const float* __restrict__ Wg,
                                               const float* __restrict__ Wr,
                                               unsigned short* __restrict__ wf) {
    const int tid = blockIdx.x * 256 + threadIdx.x;   // grid*256 == NL*2*16384
    const int l = tid >> 15;
    const int m = (tid >> 14) & 1;
    const int e = tid & 16383;
    const int k = e >> 7, n = e & 127;
    const float* W = (m == 0 ? Wg : Wr) + l * 16384;
    const float v = W[e];
    const int s = k >> 5, q = (k >> 3) & 3, j = k & 7, t = n >> 4;
    const int ln = (q << 4) | (n & 15);
    const int idx = ((s * 8 + t) * 64 + ln) * 8 + j;
    wf[(l * 2 + m) * 16384 + idx] = f2bf(v);
}

// ---------------- CSR build: histogram -> 3-phase scan -> fill ----------------
__global__ __launch_bounds__(256) void k_hist(const int* __restrict__ dst, int* cnt) {
    const int e = blockIdx.x * 256 + threadIdx.x;   // grid == NE
    atomicAdd(&cnt[dst[e]], 1);
}

__global__ __launch_bounds__(256) void k_scan1(const int* __restrict__ cnt,
                                               int* __restrict__ bsum) {
    const int tid = threadIdx.x;
    int v = cnt[blockIdx.x * 256 + tid];
    #pragma unroll
    for (int off = 1; off < 64; off <<= 1) v += __shfl_xor(v, off, 64);
    __shared__ int ws[4];
    if ((tid & 63) == 0) ws[tid >> 6] = v;
    __syncthreads();
    if (tid == 0) bsum[blockIdx.x] = ws[0] + ws[1] + ws[2] + ws[3];
}

__global__ __launch_bounds__(512) void k_scan2(const int* __restrict__ bsum,
                                               int* __restrict__ boff) {
    __shared__ int s[512];
    const int t = threadIdx.x;
    const int v = (t < NB) ? bsum[t] : 0;
    s[t] = v;
    __syncthreads();
    for (int off = 1; off < 512; off <<= 1) {
        const int u = (t >= off) ? s[t - off] : 0;
        __syncthreads();
        s[t] += u;
        __syncthreads();
    }
    if (t < NB) boff[t] = s[t] - v;   // exclusive
}

__global__ __launch_bounds__(256) void k_scan3(const int* __restrict__ cnt,
                                               const int* __restrict__ boff,
                                               int* __restrict__ rowptr,
                                               int* __restrict__ offs) {
    const int tid = threadIdx.x;
    const int t = blockIdx.x * 256 + tid;
    const int lane = tid & 63;
    const int v = cnt[t];
    int inc = v;
    #pragma unroll
    for (int off = 1; off < 64; off <<= 1) {
        const int u = __shfl_up(inc, off, 64);
        if (lane >= off) inc += u;
    }
    __shared__ int ws[4];
    if (lane == 63) ws[tid >> 6] = inc;
    __syncthreads();
    const int w = tid >> 6;
    int waveoff = 0;
    for (int i = 0; i < 4; ++i) waveoff += (i < w) ? ws[i] : 0;
    const int excl = boff[blockIdx.x] + waveoff + inc - v;
    rowptr[t] = excl;
    offs[t] = excl;
    if (blockIdx.x == NB - 1 && tid == 255) rowptr[NN] = NE;
}

__global__ __launch_bounds__(256) void k_fill(const int* __restrict__ src,
                                              const int* __restrict__ dst,
                                              int* offs, int* __restrict__ col) {
    const int e = blockIdx.x * 256 + threadIdx.x;   // grid == NE
    const int pos = atomicAdd(&offs[dst[e]], 1);
    col[pos] = src[e];
}

// ---------------- BN affine-coefficient helpers ----------------
__global__ __launch_bounds__(256) void k_prep(float* __restrict__ ab0) {
    ab0[threadIdx.x] = (threadIdx.x < 128) ? 1.0f : 0.0f;   // identity for layer 0 input
}

// reduce NREP replicated partial-sum buffers -> affine (a,b) for next stage
__global__ __launch_bounds__(128) void k_stats(const float* __restrict__ srep,
                                               const float* __restrict__ gamma,
                                               const float* __restrict__ beta,
                                               float* __restrict__ ab) {
    const int c = threadIdx.x;
    float s = 0.f, q = 0.f;
    for (int r = 0; r < NREP; ++r) {
        s += srep[r * 256 + c];
        q += srep[r * 256 + 128 + c];
    }
    const float invN = 1.0f / (float)NN;
    const float mu = s * invN;
    const float var = q * invN - mu * mu;
    const float a = gamma[c] * rsqrtf(var + EPS);
    ab[c] = a;
    ab[128 + c] = beta[c] - a * mu;
}

// ---------------- gather (BN folded): agg[row] = a * sum_e h_raw[col[e]] + deg*b ----
__global__ __launch_bounds__(256) void k_gather(const float* __restrict__ h,
                                                const int* __restrict__ rowptr,
                                                const int* __restrict__ col,
                                                const float* __restrict__ ab,
                                                float* __restrict__ agg) {
    const int wave = threadIdx.x >> 6;
    const int lane = threadIdx.x & 63;
    const int row = blockIdx.x * 4 + wave;   // grid = NN/4
    const int eb = rowptr[row];
    const int ee = rowptr[row + 1];
    const int half = lane >> 5;
    const int f = (lane & 31) * 4;
    float4 a0 = {0.f,0.f,0.f,0.f}, a1 = {0.f,0.f,0.f,0.f};
    float4 a2 = {0.f,0.f,0.f,0.f}, a3 = {0.f,0.f,0.f,0.f};
    int e = eb + half;
    for (; e + 6 < ee; e += 8) {
        const int c0 = col[e], c1 = col[e + 2], c2 = col[e + 4], c3 = col[e + 6];
        const float4 v0 = *(const float4*)(h + (size_t)c0 * DD + f);
        const float4 v1 = *(const float4*)(h + (size_t)c1 * DD + f);
        const float4 v2 = *(const float4*)(h + (size_t)c2 * DD + f);
        const float4 v3 = *(const float4*)(h + (size_t)c3 * DD + f);
        a0.x += v0.x; a0.y += v0.y; a0.z += v0.z; a0.w += v0.w;
        a1.x += v1.x; a1.y += v1.y; a1.z += v1.z; a1.w += v1.w;
        a2.x += v2.x; a2.y += v2.y; a2.z += v2.z; a2.w += v2.w;
        a3.x += v3.x; a3.y += v3.y; a3.z += v3.z; a3.w += v3.w;
    }
    for (; e < ee; e += 2) {
        const int c = col[e];
        const float4 v = *(const float4*)(h + (size_t)c * DD + f);
        a0.x += v.x; a0.y += v.y; a0.z += v.z; a0.w += v.w;
    }
    float4 s;
    s.x = (a0.x + a1.x) + (a2.x + a3.x);
    s.y = (a0.y + a1.y) + (a2.y + a3.y);
    s.z = (a0.z + a1.z) + (a2.z + a3.z);
    s.w = (a0.w + a1.w) + (a2.w + a3.w);
    s.x += __shfl_xor(s.x, 32, 64);
    s.y += __shfl_xor(s.y, 32, 64);
    s.z += __shfl_xor(s.z, 32, 64);
    s.w += __shfl_xor(s.w, 32, 64);
    if (half == 0) {
        const float deg = (float)(ee - eb);
        const float4 av = *(const float4*)(ab + f);
        const float4 bv = *(const float4*)(ab + 128 + f);
        float4 o;
        o.x = fmaf(av.x, s.x, deg * bv.x);
        o.y = fmaf(av.y, s.y, deg * bv.y);
        o.z = fmaf(av.z, s.z, deg * bv.z);
        o.w = fmaf(av.w, s.w, deg * bv.w);
        *(float4*)(agg + (size_t)row * DD + f) = o;
    }
}

// ---------------- fused layer GEMMs via bf16 MFMA (no weight LDS) ----------------
// One 64-row tile per block (round-1 memory pattern, known-clean FETCH/WRITE).
// B-frags read DIRECTLY from global frag-ordered wfrag (64KB/layer, L2-resident,
// lane-contiguous 16B -> coalesced). No staging copy, no drain barrier, LDS 1KB
// -> 4 blocks/CU (vs 2 when 65KB-LDS-capped).
__global__ __launch_bounds__(256, 4) void k_layer(const float* __restrict__ hin,
                                                  const float* __restrict__ aggin,
                                                  const unsigned short* __restrict__ wfrag,
                                                  const float* __restrict__ bg,
                                                  const float* __restrict__ br,
                                                  const float* __restrict__ ab,
                                                  float* __restrict__ h2out,
                                                  float* __restrict__ sumrep) {
    __shared__ float sSum[256];
    const int tid = threadIdx.x;
    sSum[tid] = 0.0f;
    __syncthreads();

    const int w = tid >> 6;          // wave 0..3
    const int lane = tid & 63;
    const int ln15 = lane & 15;
    const int q = lane >> 4;
    const int r0 = blockIdx.x * 64 + w * 16;   // wave's 16-row M-tile base
    const int arow = r0 + ln15;                // row this lane's A/H frag holds

    const short8* __restrict__ wgf = (const short8*)wfrag;   // 2048 short8 (frag-ordered Wg)
    const short8* __restrict__ wrf = wgf + 2048;             // frag-ordered Wr

    f32x4 accg[8], accr[8];
    #pragma unroll
    for (int t = 0; t < 8; ++t) {
        accg[t] = (f32x4){0.f, 0.f, 0.f, 0.f};
        accr[t] = (f32x4){0.f, 0.f, 0.f, 0.f};
    }

    #pragma unroll
    for (int s = 0; s < 4; ++s) {
        const int kk = s * 32 + q * 8;
        const float4 a0 = *(const float4*)(aggin + (size_t)arow * DD + kk);
        const float4 a1 = *(const float4*)(aggin + (size_t)arow * DD + kk + 4);
        const float4 h0 = *(const float4*)(hin + (size_t)arow * DD + kk);
        const float4 h1 = *(const float4*)(hin + (size_t)arow * DD + kk + 4);
        const float4 av0 = *(const float4*)(ab + kk);
        const float4 av1 = *(const float4*)(ab + kk + 4);
        const float4 bv0 = *(const float4*)(ab + 128 + kk);
        const float4 bv1 = *(const float4*)(ab + 128 + kk + 4);
        short8 af, hf;
        af[0] = (short)f2bf(a0.x); af[1] = (short)f2bf(a0.y);
        af[2] = (short)f2bf(a0.z); af[3] = (short)f2bf(a0.w);
        af[4] = (short)f2bf(a1.x); af[5] = (short)f2bf(a1.y);
        af[6] = (short)f2bf(a1.z); af[7] = (short)f2bf(a1.w);
        hf[0] = (short)f2bf(fmaf(av0.x, h0.x, bv0.x));
        hf[1] = (short)f2bf(fmaf(av0.y, h0.y, bv0.y));
        hf[2] = (short)f2bf(fmaf(av0.z, h0.z, bv0.z));
        hf[3] = (short)f2bf(fmaf(av0.w, h0.w, bv0.w));
        hf[4] = (short)f2bf(fmaf(av1.x, h1.x, bv1.x));
        hf[5] = (short)f2bf(fmaf(av1.y, h1.y, bv1.y));
        hf[6] = (short)f2bf(fmaf(av1.z, h1.z, bv1.z));
        hf[7] = (short)f2bf(fmaf(av1.w, h1.w, bv1.w));
        const int fb = s * 512;   // frag base for this k-step, in short8 units
        #pragma unroll
        for (int t = 0; t < 8; ++t) {
            const short8 bgf = wgf[fb + t * 64 + lane];
            const short8 brf = wrf[fb + t * 64 + lane];
            accg[t] = __builtin_amdgcn_mfma_f32_16x16x32_bf16(af, bgf, accg[t], 0, 0, 0);
            accr[t] = __builtin_amdgcn_mfma_f32_16x16x32_bf16(hf, brf, accr[t], 0, 0, 0);
        }
    }

    // epilogue: bias + relu + add, store h2, fused BN partial sums
    #pragma unroll
    for (int t = 0; t < 8; ++t) {
        const int c = t * 16 + ln15;
        const float bgc = bg[c];
        const float brc = br[c];
        float sv = 0.f, qv = 0.f;
        #pragma unroll
        for (int r = 0; r < 4; ++r) {
            const int row = r0 + q * 4 + r;
            const float v = fmaxf(accg[t][r] + bgc, 0.f) + fmaxf(accr[t][r] + brc, 0.f);
            h2out[(size_t)row * DD + c] = v;
            sv += v; qv += v * v;
        }
        sv += __shfl_xor(sv, 16, 64); sv += __shfl_xor(sv, 32, 64);
        qv += __shfl_xor(qv, 16, 64); qv += __shfl_xor(qv, 32, 64);
        if (q == 0) {
            atomicAdd(&sSum[c], sv);
            atomicAdd(&sSum[128 + c], qv);
        }
    }
    __syncthreads();
    atomicAdd(&sumrep[(blockIdx.x & (NREP - 1)) * 256 + tid], sSum[tid]);
}

// ---------------- BatchNorm normalize (final layer): pure affine ----------------
__global__ __launch_bounds__(256) void k_bn(const float* __restrict__ h2,
                                            const float* __restrict__ ab,
                                            float* __restrict__ out) {
    const int t = blockIdx.x * 256 + threadIdx.x;  // NN*32 threads
    const size_t base = (size_t)t * 4;
    const int c = (int)(base & 127);
    const float4 v = *(const float4*)(h2 + base);
    const float4 a = *(const float4*)(ab + c);
    const float4 b = *(const float4*)(ab + 128 + c);
    float4 o;
    o.x = fmaf(a.x, v.x, b.x);
    o.y = fmaf(a.y, v.y, b.y);
    o.z = fmaf(a.z, v.z, b.z);
    o.w = fmaf(a.w, v.w, b.w);
    *(float4*)(out + base) = o;
}

extern "C" void kernel_launch(void* const* d_in, const int* in_sizes, int n_in,
                              void* d_out, int out_size, void* d_ws, size_t ws_size,
                              hipStream_t stream) {
    const float* X     = (const float*)d_in[0];
    const int*   src   = (const int*)d_in[1];
    const int*   dst   = (const int*)d_in[2];
    const float* Wi    = (const float*)d_in[3];
    const float* Wg    = (const float*)d_in[4];
    const float* bg    = (const float*)d_in[5];
    const float* Wr    = (const float*)d_in[6];
    const float* br    = (const float*)d_in[7];
    const float* gamma = (const float*)d_in[8];
    const float* beta  = (const float*)d_in[9];
    float* out = (float*)d_out;

    float* h      = (float*)d_ws;                         // [NN*DD]
    float* agg    = h + (size_t)NN * DD;                  // [NN*DD]
    float* sumrep = agg + (size_t)NN * DD;                // [NL*NREP*256]
    float* abv    = sumrep + (size_t)NL * NREP * 256;     // [(NL+1)*2*DD]  a/b per stage
    unsigned short* wfrag = (unsigned short*)(abv + (NL + 1) * 2 * DD);  // bf16 frags
    int* rowptr = (int*)(wfrag + NL * 2 * 16384);         // [NN+1]
    int* col    = rowptr + NN + 1;                        // [NE]
    int* bsum   = col + NE;                               // [NB]
    int* boff   = bsum + NB;                              // [NB]
    // CSR-build scratch aliased into agg (dead once k_fill completes)
    int* cnt    = (int*)agg;                              // [NN]
    int* offs   = cnt + NN;                               // [NN]

    hipMemsetAsync(sumrep, 0, (size_t)NL * NREP * 256 * sizeof(float), stream);
    hipMemsetAsync(cnt, 0, NN * sizeof(int), stream);

    k_prep<<<1, 256, 0, stream>>>(abv);               // identity a=1,b=0 for layer 0
    k_init<<<NN / 64, 256, 0, stream>>>(X, Wi, h);
    k_wprep<<<(NL * 2 * 16384) / 256, 256, 0, stream>>>(Wg, Wr, wfrag);
    k_hist<<<NE / 256, 256, 0, stream>>>(dst, cnt);
    k_scan1<<<NB, 256, 0, stream>>>(cnt, bsum);
    k_scan2<<<1, 512, 0, stream>>>(bsum, boff);
    k_scan3<<<NB, 256, 0, stream>>>(cnt, boff, rowptr, offs);
    k_fill<<<NE / 256, 256, 0, stream>>>(src, dst, offs, col);

    // raw-activation buffers alternate: h -> out -> h -> out (final BN in-place on out)
    const float* hcur = h;
    float* h2bufs[NL] = { out, h, out };
    for (int l = 0; l < NL; ++l) {
        const float* abl = abv + l * 2 * DD;
        float* h2 = h2bufs[l];
        k_gather<<<NN / 4, 256, 0, stream>>>(hcur, rowptr, col, abl, agg);
        k_layer<<<NT, 256, 0, stream>>>(hcur, agg,
                                        wfrag + l * 2 * 16384,
                                        bg + l * DD, br + l * DD,
                                        abl, h2, sumrep + (size_t)l * NREP * 256);
        k_stats<<<1, 128, 0, stream>>>(sumrep + (size_t)l * NREP * 256, gamma + l * DD,
                                       beta + l * DD, abv + (l + 1) * 2 * DD);
        if (l == NL - 1) {
            k_bn<<<(NN * 32) / 256, 256, 0, stream>>>(h2, abv + NL * 2 * DD, out);
        }
        hcur = h2;
    }
}

// Round 4
// 348.811 us; speedup vs baseline: 1.4977x; 1.1064x over previous
//
#include <hip/hip_runtime.h>

#define NN 74240      // nodes
#define NE 593920     // edges
#define DIN 75
#define DD 128
#define NL 3
#define EPS 1e-5f
#define NB 290        // scan blocks: 290*256 == NN
#define NT (NN / 64)  // 1160 row-tiles for k_layer
#define NREP 64       // replicated BN-sum buffers

typedef __attribute__((ext_vector_type(8))) short short8;   // 8 bf16 = 4 VGPRs (MFMA A/B frag)
typedef __attribute__((ext_vector_type(4))) float f32x4;    // MFMA C/D frag

// fp32 -> bf16 with round-to-nearest-even
static __device__ __forceinline__ unsigned short f2bf(float f) {
    union { float f; unsigned u; } v; v.f = f;
    unsigned u = v.u;
    unsigned r = (u + 0x7fffu + ((u >> 16) & 1u)) >> 16;
    return (unsigned short)r;
}

// bf16 -> fp32 (exact)
static __device__ __forceinline__ float bf2f(unsigned short s) {
    union { unsigned u; float f; } v; v.u = ((unsigned)s) << 16; return v.f;
}

// ---------------- init GEMM: h_bf16 = bf16(X @ W_init)  ([NN,75] @ [75,128]) --------
// 256 threads = 4 waves per 64-row tile; wave w owns cols [w*32, w*32+32).
// Col-group is wave-uniform (readfirstlane) -> W loads are scalar s_load broadcasts.
__global__ __launch_bounds__(256) void k_init(const float* __restrict__ X,
                                              const float* __restrict__ W,
                                              unsigned short* __restrict__ hb) {
    __shared__ float sX[64 * DIN];            // 19200 B -> 8 blocks/CU LDS cap
    const int tid = threadIdx.x;
    const int r0 = blockIdx.x * 64;
    {   // stage 64 rows of X, float4-vectorized (64*75/4 = 1200 float4)
        const float4* Xv = (const float4*)(X + (size_t)r0 * DIN);
        float4* sv = (float4*)sX;
        #pragma unroll
        for (int i = 0; i < 4; ++i) sv[tid + i * 256] = Xv[tid + i * 256];
        if (tid < 1200 - 1024) sv[tid + 1024] = Xv[tid + 1024];
    }
    __syncthreads();
    const int lane = tid & 63;
    const int cg = __builtin_amdgcn_readfirstlane(tid >> 6) * 32;  // wave-uniform col group
    const float* xr = sX + lane * DIN;
    float acc[32];
    #pragma unroll
    for (int j = 0; j < 32; ++j) acc[j] = 0.0f;
    #pragma unroll 5
    for (int k = 0; k < DIN; ++k) {
        const float a = xr[k];
        const float* wk = W + k * DD + cg;    // uniform address -> scalar load
        #pragma unroll
        for (int j = 0; j < 32; ++j) acc[j] = fmaf(a, wk[j], acc[j]);
    }
    unsigned short* hrow = hb + (size_t)(r0 + lane) * DD + cg;
    #pragma unroll
    for (int j8 = 0; j8 < 4; ++j8) {
        short8 o;
        #pragma unroll
        for (int j = 0; j < 8; ++j) o[j] = (short)f2bf(acc[j8 * 8 + j]);
        *(short8*)(hrow + j8 * 8) = o;
    }
}

// ---------------- weight prepack: fp32 [k][n] -> frag-ordered bf16 ----------------
// frag flat index: ((s*8 + t)*64 + (q*16 + (n&15)))*8 + j  with s=k/32, q=(k/8)%4, j=k%8, t=n/16
// -> each lane's B-frag is one contiguous 16B chunk (coalesced global b128 reads).
__global__ __launch_bounds__(256) void k_wprep(const float* __restrict__ Wg,
                                               const float* __restrict__ Wr,
                                               unsigned short* __restrict__ wf) {
    const int tid = blockIdx.x * 256 + threadIdx.x;   // grid*256 == NL*2*16384
    const int l = tid >> 15;
    const int m = (tid >> 14) & 1;
    const int e = tid & 16383;
    const int k = e >> 7, n = e & 127;
    const float* W = (m == 0 ? Wg : Wr) + l * 16384;
    const float v = W[e];
    const int s = k >> 5, q = (k >> 3) & 3, j = k & 7, t = n >> 4;
    const int ln = (q << 4) | (n & 15);
    const int idx = ((s * 8 + t) * 64 + ln) * 8 + j;
    wf[(l * 2 + m) * 16384 + idx] = f2bf(v);
}

// ---------------- CSR build: histogram -> 3-phase scan -> fill ----------------
__global__ __launch_bounds__(256) void k_hist(const int* __restrict__ dst, int* cnt) {
    const int e = blockIdx.x * 256 + threadIdx.x;   // grid == NE
    atomicAdd(&cnt[dst[e]], 1);
}

__global__ __launch_bounds__(256) void k_scan1(const int* __restrict__ cnt,
                                               int* __restrict__ bsum) {
    const int tid = threadIdx.x;
    int v = cnt[blockIdx.x * 256 + tid];
    #pragma unroll
    for (int off = 1; off < 64; off <<= 1) v += __shfl_xor(v, off, 64);
    __shared__ int ws[4];
    if ((tid & 63) == 0) ws[tid >> 6] = v;
    __syncthreads();
    if (tid == 0) bsum[blockIdx.x] = ws[0] + ws[1] + ws[2] + ws[3];
}

__global__ __launch_bounds__(512) void k_scan2(const int* __restrict__ bsum,
                                               int* __restrict__ boff) {
    __shared__ int s[512];
    const int t = threadIdx.x;
    const int v = (t < NB) ? bsum[t] : 0;
    s[t] = v;
    __syncthreads();
    for (int off = 1; off < 512; off <<= 1) {
        const int u = (t >= off) ? s[t - off] : 0;
        __syncthreads();
        s[t] += u;
        __syncthreads();
    }
    if (t < NB) boff[t] = s[t] - v;   // exclusive
}

__global__ __launch_bounds__(256) void k_scan3(const int* __restrict__ cnt,
                                               const int* __restrict__ boff,
                                               int* __restrict__ rowptr,
                                               int* __restrict__ offs) {
    const int tid = threadIdx.x;
    const int t = blockIdx.x * 256 + tid;
    const int lane = tid & 63;
    const int v = cnt[t];
    int inc = v;
    #pragma unroll
    for (int off = 1; off < 64; off <<= 1) {
        const int u = __shfl_up(inc, off, 64);
        if (lane >= off) inc += u;
    }
    __shared__ int ws[4];
    if (lane == 63) ws[tid >> 6] = inc;
    __syncthreads();
    const int w = tid >> 6;
    int waveoff = 0;
    for (int i = 0; i < 4; ++i) waveoff += (i < w) ? ws[i] : 0;
    const int excl = boff[blockIdx.x] + waveoff + inc - v;
    rowptr[t] = excl;
    offs[t] = excl;
    if (blockIdx.x == NB - 1 && tid == 255) rowptr[NN] = NE;
}

__global__ __launch_bounds__(256) void k_fill(const int* __restrict__ src,
                                              const int* __restrict__ dst,
                                              int* offs, int* __restrict__ col) {
    const int e = blockIdx.x * 256 + threadIdx.x;   // grid == NE
    const int pos = atomicAdd(&offs[dst[e]], 1);
    col[pos] = src[e];
}

// ---------------- BN affine-coefficient helpers ----------------
__global__ __launch_bounds__(256) void k_prep(float* __restrict__ ab0) {
    ab0[threadIdx.x] = (threadIdx.x < 128) ? 1.0f : 0.0f;   // identity for layer 0 input
}

// reduce NREP replicated partial-sum buffers -> affine (a,b) for next stage
__global__ __launch_bounds__(128) void k_stats(const float* __restrict__ srep,
                                               const float* __restrict__ gamma,
                                               const float* __restrict__ beta,
                                               float* __restrict__ ab) {
    const int c = threadIdx.x;
    float s = 0.f, q = 0.f;
    for (int r = 0; r < NREP; ++r) {
        s += srep[r * 256 + c];
        q += srep[r * 256 + 128 + c];
    }
    const float invN = 1.0f / (float)NN;
    const float mu = s * invN;
    const float var = q * invN - mu * mu;
    const float a = gamma[c] * rsqrtf(var + EPS);
    ab[c] = a;
    ab[128 + c] = beta[c] - a * mu;
}

// ---------------- gather (BN folded): aggb[row] = bf16(a * sum_e hb[col[e]] + deg*b) --
// hb rows are 256B (bf16) -> random-gather fetch halves vs fp32. Output is row-major
// bf16 with affine applied = ready-made MFMA A-fragments for k_layer.
__global__ __launch_bounds__(256) void k_gather(const unsigned short* __restrict__ hb,
                                                const int* __restrict__ rowptr,
                                                const int* __restrict__ col,
                                                const float* __restrict__ ab,
                                                unsigned short* __restrict__ aggb) {
    const int wave = threadIdx.x >> 6;
    const int lane = threadIdx.x & 63;
    const int row = blockIdx.x * 4 + wave;   // grid = NN/4
    const int eb = rowptr[row];
    const int ee = rowptr[row + 1];
    const int half = lane >> 5;
    const int f = (lane & 31) * 4;           // 4 channels per lane
    float4 a0 = {0.f,0.f,0.f,0.f}, a1 = {0.f,0.f,0.f,0.f};
    float4 a2 = {0.f,0.f,0.f,0.f}, a3 = {0.f,0.f,0.f,0.f};
    int e = eb + half;
    for (; e + 6 < ee; e += 8) {
        const int c0 = col[e], c1 = col[e + 2], c2 = col[e + 4], c3 = col[e + 6];
        const ushort4 v0 = *(const ushort4*)(hb + (size_t)c0 * DD + f);
        const ushort4 v1 = *(const ushort4*)(hb + (size_t)c1 * DD + f);
        const ushort4 v2 = *(const ushort4*)(hb + (size_t)c2 * DD + f);
        const ushort4 v3 = *(const ushort4*)(hb + (size_t)c3 * DD + f);
        a0.x += bf2f(v0.x); a0.y += bf2f(v0.y); a0.z += bf2f(v0.z); a0.w += bf2f(v0.w);
        a1.x += bf2f(v1.x); a1.y += bf2f(v1.y); a1.z += bf2f(v1.z); a1.w += bf2f(v1.w);
        a2.x += bf2f(v2.x); a2.y += bf2f(v2.y); a2.z += bf2f(v2.z); a2.w += bf2f(v2.w);
        a3.x += bf2f(v3.x); a3.y += bf2f(v3.y); a3.z += bf2f(v3.z); a3.w += bf2f(v3.w);
    }
    for (; e < ee; e += 2) {
        const int c = col[e];
        const ushort4 v = *(const ushort4*)(hb + (size_t)c * DD + f);
        a0.x += bf2f(v.x); a0.y += bf2f(v.y); a0.z += bf2f(v.z); a0.w += bf2f(v.w);
    }
    float4 s;
    s.x = (a0.x + a1.x) + (a2.x + a3.x);
    s.y = (a0.y + a1.y) + (a2.y + a3.y);
    s.z = (a0.z + a1.z) + (a2.z + a3.z);
    s.w = (a0.w + a1.w) + (a2.w + a3.w);
    s.x += __shfl_xor(s.x, 32, 64);
    s.y += __shfl_xor(s.y, 32, 64);
    s.z += __shfl_xor(s.z, 32, 64);
    s.w += __shfl_xor(s.w, 32, 64);
    if (half == 0) {
        const float deg = (float)(ee - eb);
        const float4 av = *(const float4*)(ab + f);
        const float4 bv = *(const float4*)(ab + 128 + f);
        ushort4 o;
        o.x = f2bf(fmaf(av.x, s.x, deg * bv.x));
        o.y = f2bf(fmaf(av.y, s.y, deg * bv.y));
        o.z = f2bf(fmaf(av.z, s.z, deg * bv.z));
        o.w = f2bf(fmaf(av.w, s.w, deg * bv.w));
        *(ushort4*)(aggb + (size_t)row * DD + f) = o;
    }
}

// ---------------- fused layer GEMMs via bf16 MFMA (no weight LDS, bf16 I/O) --------
// One 64-row tile per block. B-frags read directly from global frag-ordered wfrag
// (64KB/layer, L2-resident). A-frags = direct short8 loads from aggb (affine already
// applied by k_gather). H-frags = bf16 hin + affine. Output h2 bf16 (fp32 BN sums).
__global__ __launch_bounds__(256, 4) void k_layer(const unsigned short* __restrict__ hin,
                                                  const unsigned short* __restrict__ aggb,
                                                  const unsigned short* __restrict__ wfrag,
                                                  const float* __restrict__ bg,
                                                  const float* __restrict__ br,
                                                  const float* __restrict__ ab,
                                                  unsigned short* __restrict__ h2b,
                                                  float* __restrict__ sumrep) {
    __shared__ float sSum[256];
    const int tid = threadIdx.x;
    sSum[tid] = 0.0f;
    __syncthreads();

    const int w = tid >> 6;          // wave 0..3
    const int lane = tid & 63;
    const int ln15 = lane & 15;
    const int q = lane >> 4;
    const int r0 = blockIdx.x * 64 + w * 16;   // wave's 16-row M-tile base
    const int arow = r0 + ln15;                // row this lane's A/H frag holds

    const short8* __restrict__ wgf = (const short8*)wfrag;   // 2048 short8 (frag-ordered Wg)
    const short8* __restrict__ wrf = wgf + 2048;             // frag-ordered Wr

    f32x4 accg[8], accr[8];
    #pragma unroll
    for (int t = 0; t < 8; ++t) {
        accg[t] = (f32x4){0.f, 0.f, 0.f, 0.f};
        accr[t] = (f32x4){0.f, 0.f, 0.f, 0.f};
    }

    #pragma unroll
    for (int s = 0; s < 4; ++s) {
        const int kk = s * 32 + q * 8;
        const short8 af = *(const short8*)(aggb + (size_t)arow * DD + kk);  // frag-ready
        const short8 hr = *(const short8*)(hin + (size_t)arow * DD + kk);
        const float4 av0 = *(const float4*)(ab + kk);
        const float4 av1 = *(const float4*)(ab + kk + 4);
        const float4 bv0 = *(const float4*)(ab + 128 + kk);
        const float4 bv1 = *(const float4*)(ab + 128 + kk + 4);
        short8 hf;
        hf[0] = (short)f2bf(fmaf(av0.x, bf2f((unsigned short)hr[0]), bv0.x));
        hf[1] = (short)f2bf(fmaf(av0.y, bf2f((unsigned short)hr[1]), bv0.y));
        hf[2] = (short)f2bf(fmaf(av0.z, bf2f((unsigned short)hr[2]), bv0.z));
        hf[3] = (short)f2bf(fmaf(av0.w, bf2f((unsigned short)hr[3]), bv0.w));
        hf[4] = (short)f2bf(fmaf(av1.x, bf2f((unsigned short)hr[4]), bv1.x));
        hf[5] = (short)f2bf(fmaf(av1.y, bf2f((unsigned short)hr[5]), bv1.y));
        hf[6] = (short)f2bf(fmaf(av1.z, bf2f((unsigned short)hr[6]), bv1.z));
        hf[7] = (short)f2bf(fmaf(av1.w, bf2f((unsigned short)hr[7]), bv1.w));
        const int fb = s * 512;   // frag base for this k-step, in short8 units
        #pragma unroll
        for (int t = 0; t < 8; ++t) {
            const short8 bgf = wgf[fb + t * 64 + lane];
            const short8 brf = wrf[fb + t * 64 + lane];
            accg[t] = __builtin_amdgcn_mfma_f32_16x16x32_bf16(af, bgf, accg[t], 0, 0, 0);
            accr[t] = __builtin_amdgcn_mfma_f32_16x16x32_bf16(hf, brf, accr[t], 0, 0, 0);
        }
    }

    // epilogue: bias + relu + add, store bf16 h2, fused fp32 BN partial sums
    #pragma unroll
    for (int t = 0; t < 8; ++t) {
        const int c = t * 16 + ln15;
        const float bgc = bg[c];
        const float brc = br[c];
        float sv = 0.f, qv = 0.f;
        #pragma unroll
        for (int r = 0; r < 4; ++r) {
            const int row = r0 + q * 4 + r;
            const float v = fmaxf(accg[t][r] + bgc, 0.f) + fmaxf(accr[t][r] + brc, 0.f);
            h2b[(size_t)row * DD + c] = f2bf(v);
            sv += v; qv += v * v;
        }
        sv += __shfl_xor(sv, 16, 64); sv += __shfl_xor(sv, 32, 64);
        qv += __shfl_xor(qv, 16, 64); qv += __shfl_xor(qv, 32, 64);
        if (q == 0) {
            atomicAdd(&sSum[c], sv);
            atomicAdd(&sSum[128 + c], qv);
        }
    }
    __syncthreads();
    atomicAdd(&sumrep[(blockIdx.x & (NREP - 1)) * 256 + tid], sSum[tid]);
}

// ---------------- BatchNorm normalize (final layer): pure affine, bf16 in fp32 out --
__global__ __launch_bounds__(256) void k_bn(const unsigned short* __restrict__ h2b,
                                            const float* __restrict__ ab,
                                            float* __restrict__ out) {
    const int t = blockIdx.x * 256 + threadIdx.x;  // NN*32 threads
    const size_t base = (size_t)t * 4;
    const int c = (int)(base & 127);
    const ushort4 v = *(const ushort4*)(h2b + base);
    const float4 a = *(const float4*)(ab + c);
    const float4 b = *(const float4*)(ab + 128 + c);
    float4 o;
    o.x = fmaf(a.x, bf2f(v.x), b.x);
    o.y = fmaf(a.y, bf2f(v.y), b.y);
    o.z = fmaf(a.z, bf2f(v.z), b.z);
    o.w = fmaf(a.w, bf2f(v.w), b.w);
    *(float4*)(out + base) = o;
}

extern "C" void kernel_launch(void* const* d_in, const int* in_sizes, int n_in,
                              void* d_out, int out_size, void* d_ws, size_t ws_size,
                              hipStream_t stream) {
    const float* X     = (const float*)d_in[0];
    const int*   src   = (const int*)d_in[1];
    const int*   dst   = (const int*)d_in[2];
    const float* Wi    = (const float*)d_in[3];
    const float* Wg    = (const float*)d_in[4];
    const float* bg    = (const float*)d_in[5];
    const float* Wr    = (const float*)d_in[6];
    const float* br    = (const float*)d_in[7];
    const float* gamma = (const float*)d_in[8];
    const float* beta  = (const float*)d_in[9];
    float* out = (float*)d_out;

    unsigned short* hA   = (unsigned short*)d_ws;         // [NN*DD] bf16
    unsigned short* hB   = hA + (size_t)NN * DD;          // [NN*DD] bf16
    unsigned short* aggb = hB + (size_t)NN * DD;          // [NN*DD] bf16
    float* sumrep = (float*)(aggb + (size_t)NN * DD);     // [NL*NREP*256]
    float* abv    = sumrep + (size_t)NL * NREP * 256;     // [(NL+1)*2*DD]  a/b per stage
    unsigned short* wfrag = (unsigned short*)(abv + (NL + 1) * 2 * DD);  // bf16 frags
    int* rowptr = (int*)(wfrag + NL * 2 * 16384);         // [NN+1]
    int* col    = rowptr + NN + 1;                        // [NE]
    int* bsum   = col + NE;                               // [NB]
    int* boff   = bsum + NB;                              // [NB]
    // CSR-build scratch aliased into aggb (dead once k_fill completes)
    int* cnt    = (int*)aggb;                             // [NN]
    int* offs   = cnt + NN;                               // [NN]

    hipMemsetAsync(sumrep, 0, (size_t)NL * NREP * 256 * sizeof(float), stream);
    hipMemsetAsync(cnt, 0, NN * sizeof(int), stream);

    k_prep<<<1, 256, 0, stream>>>(abv);               // identity a=1,b=0 for layer 0
    k_init<<<NN / 64, 256, 0, stream>>>(X, Wi, hA);
    k_wprep<<<(NL * 2 * 16384) / 256, 256, 0, stream>>>(Wg, Wr, wfrag);
    k_hist<<<NE / 256, 256, 0, stream>>>(dst, cnt);
    k_scan1<<<NB, 256, 0, stream>>>(cnt, bsum);
    k_scan2<<<1, 512, 0, stream>>>(bsum, boff);
    k_scan3<<<NB, 256, 0, stream>>>(cnt, boff, rowptr, offs);
    k_fill<<<NE / 256, 256, 0, stream>>>(src, dst, offs, col);

    // bf16 activation ping-pong: hA -> hB -> hA -> hB; k_bn reads final hB
    const unsigned short* hcur = hA;
    unsigned short* h2bufs[NL] = { hB, hA, hB };
    for (int l = 0; l < NL; ++l) {
        const float* abl = abv + l * 2 * DD;
        unsigned short* h2 = h2bufs[l];
        k_gather<<<NN / 4, 256, 0, stream>>>(hcur, rowptr, col, abl, aggb);
        k_layer<<<NT, 256, 0, stream>>>(hcur, aggb,
                                        wfrag + l * 2 * 16384,
                                        bg + l * DD, br + l * DD,
                                        abl, h2, sumrep + (size_t)l * NREP * 256);
        k_stats<<<1, 128, 0, stream>>>(sumrep + (size_t)l * NREP * 256, gamma + l * DD,
                                       beta + l * DD, abv + (l + 1) * 2 * DD);
        if (l == NL - 1) {
            k_bn<<<(NN * 32) / 256, 256, 0, stream>>>(h2, abv + NL * 2 * DD, out);
        }
        hcur = h2;
    }
}